// Round 8
// baseline (350.146 us; speedup 1.0000x reference)
//
#include <hip/hip_runtime.h>
#include <hip/hip_fp16.h>
#include <math.h>
#include <string.h>

constexpr int D = 128;

struct __align__(16) H8 { __half2 h[4]; };
struct __align__(8)  H4 { __half2 a, b; };
struct __align__(8)  CD { int cnt; float deg; };

typedef _Float16 half8  __attribute__((ext_vector_type(8)));
typedef float   floatx4 __attribute__((ext_vector_type(4)));
typedef int     i32x4   __attribute__((ext_vector_type(4)));
typedef int     i32x2   __attribute__((ext_vector_type(2)));

// ---- non-temporal load/store helpers (streamed data: skip L2 retention) ----
template <typename T>
__device__ __forceinline__ T ld_nt(const T* p) {
  if constexpr (sizeof(T) == 16) {
    i32x4 v = __builtin_nontemporal_load((const i32x4*)p);
    T r; memcpy(&r, &v, 16); return r;
  } else if constexpr (sizeof(T) == 8) {
    i32x2 v = __builtin_nontemporal_load((const i32x2*)p);
    T r; memcpy(&r, &v, 8); return r;
  } else {
    int v = __builtin_nontemporal_load((const int*)p);
    T r; memcpy(&r, &v, 4); return r;
  }
}
template <typename T>
__device__ __forceinline__ void st_nt(T* p, T v) {
  if constexpr (sizeof(T) == 16) {
    i32x4 t; memcpy(&t, &v, 16);
    __builtin_nontemporal_store(t, (i32x4*)p);
  } else if constexpr (sizeof(T) == 8) {
    i32x2 t; memcpy(&t, &v, 8);
    __builtin_nontemporal_store(t, (i32x2*)p);
  } else {
    int t; memcpy(&t, &v, 4);
    __builtin_nontemporal_store(t, (int*)p);
  }
}

// ---------------- preprocessing ----------------

__device__ __forceinline__ int detect64(const int* __restrict__ ei) {
  int z = 0;
#pragma unroll
  for (int i = 0; i < 8; ++i) z |= ei[2 * i + 1];
  return (z == 0) ? 1 : 0;
}

__device__ __forceinline__ void load_edge(const int* __restrict__ ei, int e, int nE,
                                          int m64, int n, int& r, int& c) {
  if (m64) { r = ei[2 * (size_t)e]; c = ei[2 * ((size_t)nE + e)]; }
  else     { r = ei[(size_t)e];     c = ei[(size_t)nE + e]; }
  r = min(max(r, 0), n - 1);
  c = min(max(c, 0), n - 1);
}

// blocks [0,3): transpose W1/W2/W3 fp32 [k][n] -> Wt fp16 [n][k].
// blocks [3,...): zero cd[].
__global__ void k_init(const float* __restrict__ W1, const float* __restrict__ W2,
                       const float* __restrict__ W3, __half* __restrict__ Wt,
                       CD* __restrict__ cd, int n) {
  __shared__ float s[128][129];
  int tid = threadIdx.x;
  if (blockIdx.x >= 3) {
    int i = (blockIdx.x - 3) * 256 + tid;
    if (i < n) *(long long*)&cd[i] = 0ll;
    return;
  }
  const float* W = blockIdx.x == 0 ? W1 : (blockIdx.x == 1 ? W2 : W3);
  __half* o = Wt + (size_t)blockIdx.x * D * D;
#pragma unroll
  for (int i = 0; i < 16; ++i) {
    int flat = i * 1024 + tid * 4;
    int k = flat >> 7;
    int nn = flat & 127;
    float4 v = *(const float4*)(W + (size_t)k * D + nn);
    s[k][nn] = v.x; s[k][nn + 1] = v.y; s[k][nn + 2] = v.z; s[k][nn + 3] = v.w;
  }
  __syncthreads();
#pragma unroll
  for (int i = 0; i < 8; ++i) {
    int flat = i * 256 + tid;
    int nn = flat >> 4;
    int k0 = (flat & 15) * 8;
    H8 hv;
#pragma unroll
    for (int t = 0; t < 4; ++t)
      hv.h[t] = __floats2half2_rn(s[k0 + 2 * t][nn], s[k0 + 2 * t + 1][nn]);
    *(H8*)(o + (size_t)nn * D + k0) = hv;
  }
}

// rank + weighted degree in ONE pass; cnt and deg share an 8B struct -> same
// cache line for both atomics. 2 edges/thread for atomic pipelining.
__global__ void k_pos(const int* __restrict__ ei, const float* __restrict__ w,
                      CD* __restrict__ cd, int2* __restrict__ rc,
                      int* __restrict__ pos, int nE, int n) {
  int base = (blockIdx.x * blockDim.x + threadIdx.x) * 2;
  int m64 = detect64(ei);
#pragma unroll
  for (int u = 0; u < 2; ++u) {
    int e = base + u;
    if (e >= nE) break;
    int r, c;
    load_edge(ei, e, nE, m64, n, r, c);
    rc[e] = make_int2(r, c);
    pos[e] = atomicAdd(&cd[c].cnt, 1);
    atomicAdd(&cd[c].deg, w[e]);
  }
}

// scan pass 1 over cd[].cnt; dinv computed here too (fused).
__global__ void k_scan1(const CD* __restrict__ cd, int* __restrict__ offs,
                        int* __restrict__ bsum, float* __restrict__ dinv, int n) {
  __shared__ int s[256];
  int t = threadIdx.x;
  int i = blockIdx.x * 256 + t;
  int v = 0;
  if (i < n) {
    CD c = cd[i];
    v = c.cnt;
    dinv[i] = rsqrtf(1.0f + c.deg);   // +1 = self-loop weight
  }
  s[t] = v;
  __syncthreads();
  for (int off = 1; off < 256; off <<= 1) {
    int x = 0;
    if (t >= off) x = s[t - off];
    __syncthreads();
    if (t >= off) s[t] += x;
    __syncthreads();
  }
  if (i < n) offs[i] = s[t] - v;
  if (t == 255) bsum[blockIdx.x] = s[255];
}

__global__ void k_scan2(const int* __restrict__ bsum, int* __restrict__ boff, int nb) {
  __shared__ int s[256];
  int t = threadIdx.x;
  int v = (t < nb) ? bsum[t] : 0;
  s[t] = v;
  __syncthreads();
  for (int off = 1; off < 256; off <<= 1) {
    int x = 0;
    if (t >= off) x = s[t - off];
    __syncthreads();
    if (t >= off) s[t] += x;
    __syncthreads();
  }
  if (t < nb) boff[t] = s[t] - v;
}

__global__ void k_scan3(int* __restrict__ offs, const int* __restrict__ boff, int n, int nE) {
  int i = blockIdx.x * 256 + threadIdx.x;
  if (i < n) offs[i] += boff[blockIdx.x];
  if (i == 0) offs[n] = nE;
}

// CSR fill + coefficient pack fused: ecf2[offs[c]+rank] = (src<<16)|fp16(dinv[src]*w).
__global__ void k_fillcoef(const int2* __restrict__ rc, const int* __restrict__ pos,
                           const float* __restrict__ w, const int* __restrict__ offs,
                           const float* __restrict__ dinv,
                           unsigned int* __restrict__ ecf2, int nE) {
  int base = (blockIdx.x * blockDim.x + threadIdx.x) * 2;
#pragma unroll
  for (int u = 0; u < 2; ++u) {
    int e = base + u;
    if (e >= nE) break;
    int2 p = rc[e];
    int idx = offs[p.y] + pos[e];
    float c = dinv[p.x] * w[e];
    ecf2[idx] = ((unsigned int)p.x << 16) |
                (unsigned int)__half_as_ushort(__float2half_rn(c));
  }
}

// ---------------- MFMA GEMM: Y(chunk layout) = half( act(A) @ W ) ----------------
// Y layout: Y[chunk][n][32] halves, chunk = feature>>5.
template <int ACT>
__device__ __forceinline__ float act_f(float x) {
  if (ACT == 1) return x > 0.f ? x : expm1f(x);
  if (ACT == 2) return 0.5f * x * (1.0f + erff(x * 0.70710678118654752440f));
  return x;
}

template <int ACT, typename AT>
__global__ __launch_bounds__(256) void k_gemm(const AT* __restrict__ A,
                                              const __half* __restrict__ Wt,
                                              __half* __restrict__ Y, int n) {
  const int wave = threadIdx.x >> 6;
  const int lane = threadIdx.x & 63;
  const int np = lane & 15;
  const int quad = lane >> 4;
  const int node = blockIdx.x * 64 + wave * 16 + np;
  const int nc = min(node, n - 1);

  half8 b[4];
#pragma unroll
  for (int s = 0; s < 4; ++s) {
    if constexpr (sizeof(AT) == 4) {
      const float* ap = (const float*)A + (size_t)nc * D + s * 32 + quad * 8;
      float4 v0 = ld_nt((const float4*)ap);
      float4 v1 = ld_nt((const float4*)(ap + 4));
      b[s][0] = (_Float16)act_f<ACT>(v0.x); b[s][1] = (_Float16)act_f<ACT>(v0.y);
      b[s][2] = (_Float16)act_f<ACT>(v0.z); b[s][3] = (_Float16)act_f<ACT>(v0.w);
      b[s][4] = (_Float16)act_f<ACT>(v1.x); b[s][5] = (_Float16)act_f<ACT>(v1.y);
      b[s][6] = (_Float16)act_f<ACT>(v1.z); b[s][7] = (_Float16)act_f<ACT>(v1.w);
    } else {
      half8 raw = ld_nt((const half8*)((const __half*)A + ((size_t)s * n + nc) * 32 + quad * 8));
#pragma unroll
      for (int t = 0; t < 8; ++t)
        b[s][t] = (_Float16)act_f<ACT>((float)raw[t]);
    }
  }

  floatx4 acc[8];
#pragma unroll
  for (int mt = 0; mt < 8; ++mt) acc[mt] = (floatx4){0.f, 0.f, 0.f, 0.f};

#pragma unroll
  for (int mt = 0; mt < 8; ++mt) {
#pragma unroll
    for (int s = 0; s < 4; ++s) {
      half8 a = *(const half8*)(Wt + (size_t)(mt * 16 + np) * D + s * 32 + quad * 8);
      acc[mt] = __builtin_amdgcn_mfma_f32_16x16x32_f16(a, b[s], acc[mt], 0, 0, 0);
    }
  }

  if (node < n) {
#pragma unroll
    for (int mt = 0; mt < 8; ++mt) {
      H4 hv;
      hv.a = __floats2half2_rn(acc[mt][0], acc[mt][1]);
      hv.b = __floats2half2_rn(acc[mt][2], acc[mt][3]);
      int f0 = mt * 16 + quad * 4;
      st_nt((H4*)(Y + ((size_t)(f0 >> 5) * n + node) * 32 + (f0 & 31)), hv);
    }
  }
}

// -------- aggregation (chunked, L2-resident gathers) --------
__device__ __forceinline__ void fmacc8(float* acc, float c, const H8& y) {
  float2 f;
  f = __half22float2(y.h[0]); acc[0] += c * f.x; acc[1] += c * f.y;
  f = __half22float2(y.h[1]); acc[2] += c * f.x; acc[3] += c * f.y;
  f = __half22float2(y.h[2]); acc[4] += c * f.x; acc[5] += c * f.y;
  f = __half22float2(y.h[3]); acc[6] += c * f.x; acc[7] += c * f.y;
}

__device__ __forceinline__ float cdecode(unsigned int u) {
  return __half2float(__ushort_as_half((unsigned short)(u & 0xffffu)));
}

template <int PRELU, typename OutT>
__global__ __launch_bounds__(256) void k_agg(const __half* __restrict__ Y,
                                             const int* __restrict__ offs,
                                             const unsigned int* __restrict__ ecf2,
                                             const float* __restrict__ dinv,
                                             const float* __restrict__ bias,
                                             const float* __restrict__ pw,
                                             OutT* __restrict__ OUT, int n) {
  const int chunk = blockIdx.x & 3;
  const int t = threadIdx.x;
  const int node = (blockIdx.x >> 2) * 32 + (t >> 3);
  const int sub = (t >> 2) & 1;   // edge half-group
  const int j = t & 3;            // 16B piece of the 64B chunk
  if (node >= n) return;
  const __half* Yc = Y + (size_t)chunk * n * 32;
  float dc = dinv[node];
  float acc[8] = {0.f, 0.f, 0.f, 0.f, 0.f, 0.f, 0.f, 0.f};
  if (sub == 0) {
    H8 ys = *(const H8*)(Yc + (size_t)node * 32 + j * 8);
    fmacc8(acc, dc, ys);
  }
  int e0 = offs[node], e1 = offs[node + 1];
  int e = e0 + sub;
  for (; e + 6 < e1; e += 8) {   // 4 gathers in flight per lane
    unsigned int u0 = ld_nt(&ecf2[e]),     u1 = ld_nt(&ecf2[e + 2]);
    unsigned int u2 = ld_nt(&ecf2[e + 4]), u3 = ld_nt(&ecf2[e + 6]);
    H8 y0 = *(const H8*)(Yc + (size_t)(u0 >> 16) * 32 + j * 8);
    H8 y1 = *(const H8*)(Yc + (size_t)(u1 >> 16) * 32 + j * 8);
    H8 y2 = *(const H8*)(Yc + (size_t)(u2 >> 16) * 32 + j * 8);
    H8 y3 = *(const H8*)(Yc + (size_t)(u3 >> 16) * 32 + j * 8);
    fmacc8(acc, cdecode(u0), y0);
    fmacc8(acc, cdecode(u1), y1);
    fmacc8(acc, cdecode(u2), y2);
    fmacc8(acc, cdecode(u3), y3);
  }
  for (; e + 2 < e1; e += 4) {   // 2 gathers in flight (common case, deg 8..13)
    unsigned int u0 = ld_nt(&ecf2[e]), u1 = ld_nt(&ecf2[e + 2]);
    H8 y0 = *(const H8*)(Yc + (size_t)(u0 >> 16) * 32 + j * 8);
    H8 y1 = *(const H8*)(Yc + (size_t)(u1 >> 16) * 32 + j * 8);
    fmacc8(acc, cdecode(u0), y0);
    fmacc8(acc, cdecode(u1), y1);
  }
  for (; e < e1; e += 2) {
    unsigned int u = ld_nt(&ecf2[e]);
    H8 y = *(const H8*)(Yc + (size_t)(u >> 16) * 32 + j * 8);
    fmacc8(acc, cdecode(u), y);
  }
#pragma unroll
  for (int i = 0; i < 8; ++i) acc[i] += __shfl_xor(acc[i], 4, 64);
  float4 b4 = *(const float4*)(bias + chunk * 32 + j * 8 + sub * 4);
  float o[4];
  o[0] = dc * acc[sub * 4 + 0] + b4.x;
  o[1] = dc * acc[sub * 4 + 1] + b4.y;
  o[2] = dc * acc[sub * 4 + 2] + b4.z;
  o[3] = dc * acc[sub * 4 + 3] + b4.w;
  if (PRELU) {
    float wv = *pw;
#pragma unroll
    for (int i = 0; i < 4; ++i) o[i] = o[i] >= 0.f ? o[i] : wv * o[i];
  }
  if constexpr (sizeof(OutT) == 4) {
    st_nt((float4*)((float*)OUT + (size_t)node * D + chunk * 32 + j * 8 + sub * 4),
          make_float4(o[0], o[1], o[2], o[3]));
  } else {
    H4 hv;
    hv.a = __floats2half2_rn(o[0], o[1]);
    hv.b = __floats2half2_rn(o[2], o[3]);
    st_nt((H4*)((__half*)OUT + ((size_t)chunk * n + node) * 32 + j * 8 + sub * 4), hv);
  }
}

// ---------------- launch ----------------
extern "C" void kernel_launch(void* const* d_in, const int* in_sizes, int n_in,
                              void* d_out, int out_size, void* d_ws, size_t ws_size,
                              hipStream_t stream) {
  const float* x  = (const float*)d_in[0];
  const int*   ei = (const int*)d_in[1];
  const float* w  = (const float*)d_in[2];
  const float* W1 = (const float*)d_in[3];
  const float* b1 = (const float*)d_in[4];
  const float* W2 = (const float*)d_in[5];
  const float* b2 = (const float*)d_in[6];
  const float* W3 = (const float*)d_in[7];
  const float* b3 = (const float*)d_in[8];
  const float* pw = (const float*)d_in[9];
  const int N = in_sizes[0] / D;
  const int E = in_sizes[2];
  float* out = (float*)d_out;

  char* wsb = (char*)d_ws;
  size_t off = 0;
  auto alloc = [&](size_t bytes) {
    void* p = wsb + off;
    off = (off + bytes + 255) & ~(size_t)255;
    return p;
  };
  float*        dinv = (float*)alloc((size_t)N * 4);
  CD*           cd   = (CD*)alloc((size_t)N * 8);
  int*          offs = (int*)alloc((size_t)(N + 1) * 4);
  int*          bsum = (int*)alloc(256 * 4);
  int*          boff = (int*)alloc(256 * 4);
  unsigned int* ecf2 = (unsigned int*)alloc((size_t)E * 4);
  __half*       Wt   = (__half*)alloc((size_t)3 * D * D * 2);
  __half*       Y    = (__half*)alloc((size_t)N * D * 2);
  __half*       h    = (__half*)alloc((size_t)N * D * 2);
  // transient buffers aliased into Y (dead before first GEMM writes Y): 12B/edge < N*D*2
  int2*         rc   = (int2*)Y;
  int*          pos  = (int*)((char*)Y + (size_t)E * 8);

  const int nb  = (N + 255) / 256;
  const int eb2 = (E + 511) / 512;

  hipLaunchKernelGGL(k_init,     dim3(3 + nb), dim3(256), 0, stream, W1, W2, W3, Wt, cd, N);
  hipLaunchKernelGGL(k_pos,      dim3(eb2), dim3(256), 0, stream, ei, w, cd, rc, pos, E, N);
  hipLaunchKernelGGL(k_scan1,    dim3(nb),  dim3(256), 0, stream, cd, offs, bsum, dinv, N);
  hipLaunchKernelGGL(k_scan2,    dim3(1),   dim3(256), 0, stream, bsum, boff, nb);
  hipLaunchKernelGGL(k_scan3,    dim3(nb),  dim3(256), 0, stream, offs, boff, N, E);
  hipLaunchKernelGGL(k_fillcoef, dim3(eb2), dim3(256), 0, stream, rc, pos, w, offs, dinv, ecf2, E);

  const int gb = (N + 63) / 64;
  const int ab = 4 * ((N + 31) / 32);

  hipLaunchKernelGGL((k_gemm<0, float>),  dim3(gb), dim3(256), 0, stream, x, Wt,             Y, N);
  hipLaunchKernelGGL((k_agg<0, __half>),  dim3(ab), dim3(256), 0, stream, Y, offs, ecf2, dinv, b1, pw, h, N);
  hipLaunchKernelGGL((k_gemm<1, __half>), dim3(gb), dim3(256), 0, stream, h, Wt + D * D,     Y, N);
  hipLaunchKernelGGL((k_agg<0, __half>),  dim3(ab), dim3(256), 0, stream, Y, offs, ecf2, dinv, b2, pw, h, N);
  hipLaunchKernelGGL((k_gemm<2, __half>), dim3(gb), dim3(256), 0, stream, h, Wt + 2 * D * D, Y, N);
  hipLaunchKernelGGL((k_agg<1, float>),   dim3(ab), dim3(256), 0, stream, Y, offs, ecf2, dinv, b3, pw, out, N);
}

// Round 9
// 328.690 us; speedup vs baseline: 1.0653x; 1.0653x over previous
//
#include <hip/hip_runtime.h>
#include <hip/hip_fp16.h>
#include <math.h>
#include <string.h>

constexpr int D = 128;

struct __align__(16) H8 { __half2 h[4]; };
struct __align__(8)  H4 { __half2 a, b; };

typedef _Float16 half8  __attribute__((ext_vector_type(8)));
typedef float   floatx4 __attribute__((ext_vector_type(4)));
typedef int     i32x4   __attribute__((ext_vector_type(4)));

// ---- non-temporal helpers: ONLY for stream-once data (no downstream reader in L2) ----
template <typename T>
__device__ __forceinline__ T ld_nt(const T* p) {
  if constexpr (sizeof(T) == 16) {
    i32x4 v = __builtin_nontemporal_load((const i32x4*)p);
    T r; memcpy(&r, &v, 16); return r;
  } else {
    int v = __builtin_nontemporal_load((const int*)p);
    T r; memcpy(&r, &v, 4); return r;
  }
}
__device__ __forceinline__ void st_nt16(void* p, float4 v) {
  i32x4 t; memcpy(&t, &v, 16);
  __builtin_nontemporal_store(t, (i32x4*)p);
}

// ---------------- preprocessing ----------------

__device__ __forceinline__ int detect64(const int* __restrict__ ei) {
  int z = 0;
#pragma unroll
  for (int i = 0; i < 8; ++i) z |= ei[2 * i + 1];
  return (z == 0) ? 1 : 0;
}

__device__ __forceinline__ void load_edge(const int* __restrict__ ei, int e, int nE,
                                          int m64, int n, int& r, int& c) {
  if (m64) { r = ei[2 * (size_t)e]; c = ei[2 * ((size_t)nE + e)]; }
  else     { r = ei[(size_t)e];     c = ei[(size_t)nE + e]; }
  r = min(max(r, 0), n - 1);
  c = min(max(c, 0), n - 1);
}

// blocks [0,3): transpose W1/W2/W3 fp32 [k][n] -> Wt fp16 [n][k]. blocks [3..): zero cnt.
__global__ void k_init(const float* __restrict__ W1, const float* __restrict__ W2,
                       const float* __restrict__ W3, __half* __restrict__ Wt,
                       int* __restrict__ cnt, int n) {
  __shared__ float s[128][129];
  int tid = threadIdx.x;
  if (blockIdx.x >= 3) {
    int i = (blockIdx.x - 3) * 256 + tid;
    if (i < n) cnt[i] = 0;
    return;
  }
  const float* W = blockIdx.x == 0 ? W1 : (blockIdx.x == 1 ? W2 : W3);
  __half* o = Wt + (size_t)blockIdx.x * D * D;
#pragma unroll
  for (int i = 0; i < 16; ++i) {
    int flat = i * 1024 + tid * 4;
    int k = flat >> 7;
    int nn = flat & 127;
    float4 v = *(const float4*)(W + (size_t)k * D + nn);
    s[k][nn] = v.x; s[k][nn + 1] = v.y; s[k][nn + 2] = v.z; s[k][nn + 3] = v.w;
  }
  __syncthreads();
#pragma unroll
  for (int i = 0; i < 8; ++i) {
    int flat = i * 256 + tid;
    int nn = flat >> 4;
    int k0 = (flat & 15) * 8;
    H8 hv;
#pragma unroll
    for (int t = 0; t < 4; ++t)
      hv.h[t] = __floats2half2_rn(s[k0 + 2 * t][nn], s[k0 + 2 * t + 1][nn]);
    *(H8*)(o + (size_t)nn * D + k0) = hv;
  }
}

// ONE atomic per edge; packed (r<<16)|c (both < 65536); rank stored for atomic-free fill.
__global__ void k_pos(const int* __restrict__ ei, int* __restrict__ cnt,
                      unsigned int* __restrict__ rcp, int* __restrict__ pos,
                      int nE, int n) {
  int e = blockIdx.x * blockDim.x + threadIdx.x;
  if (e >= nE) return;
  int m64 = detect64(ei);
  int r, c;
  load_edge(ei, e, nE, m64, n, r, c);
  rcp[e] = ((unsigned int)r << 16) | (unsigned int)c;
  pos[e] = atomicAdd(&cnt[c], 1);
}

__global__ void k_scan1(const int* __restrict__ cnt, int* __restrict__ offs,
                        int* __restrict__ bsum, int n) {
  __shared__ int s[256];
  int t = threadIdx.x;
  int i = blockIdx.x * 256 + t;
  int v = (i < n) ? cnt[i] : 0;
  s[t] = v;
  __syncthreads();
  for (int off = 1; off < 256; off <<= 1) {
    int x = 0;
    if (t >= off) x = s[t - off];
    __syncthreads();
    if (t >= off) s[t] += x;
    __syncthreads();
  }
  if (i < n) offs[i] = s[t] - v;
  if (t == 255) bsum[blockIdx.x] = s[255];
}

__global__ void k_scan2(const int* __restrict__ bsum, int* __restrict__ boff, int nb) {
  __shared__ int s[256];
  int t = threadIdx.x;
  int v = (t < nb) ? bsum[t] : 0;
  s[t] = v;
  __syncthreads();
  for (int off = 1; off < 256; off <<= 1) {
    int x = 0;
    if (t >= off) x = s[t - off];
    __syncthreads();
    if (t >= off) s[t] += x;
    __syncthreads();
  }
  if (t < nb) boff[t] = s[t] - v;
}

__global__ void k_scan3(int* __restrict__ offs, const int* __restrict__ boff, int n, int nE) {
  int i = blockIdx.x * 256 + threadIdx.x;
  if (i < n) offs[i] += boff[blockIdx.x];
  if (i == 0) offs[n] = nE;
}

// Atomic-free CSR fill: idx = offs[c] + rank. One random 8B store per edge.
__global__ void k_fill(const unsigned int* __restrict__ rcp, const int* __restrict__ pos,
                       const float* __restrict__ w, const int* __restrict__ offs,
                       int2* __restrict__ ecf, int nE) {
  int e = blockIdx.x * blockDim.x + threadIdx.x;
  if (e >= nE) return;
  unsigned int p = rcp[e];
  int idx = offs[p & 0xffffu] + pos[e];
  ecf[idx] = make_int2((int)(p >> 16), __float_as_int(w[e]));
}

// deg[c] = 1 (self loop) + sum w over CSR row (coalesced); dinv = rsqrt(deg).
__global__ void k_degdinv(const int2* __restrict__ ecf, const int* __restrict__ offs,
                          float* __restrict__ dinv, int n) {
  int i = blockIdx.x * blockDim.x + threadIdx.x;
  if (i >= n) return;
  float s = 1.0f;
  int e1 = offs[i + 1];
  for (int e = offs[i]; e < e1; ++e) s += __int_as_float(ecf[e].y);
  dinv[i] = rsqrtf(s);
}

// Pack edge -> (src<<16) | fp16(dinv[src]*w).
__global__ void k_coef(const int2* __restrict__ ecf, const float* __restrict__ dinv,
                       unsigned int* __restrict__ ecf2, int nE) {
  int e = blockIdx.x * blockDim.x + threadIdx.x;
  if (e >= nE) return;
  int2 p = ecf[e];
  float c = dinv[p.x] * __int_as_float(p.y);
  ecf2[e] = ((unsigned int)p.x << 16) |
            (unsigned int)__half_as_ushort(__float2half_rn(c));
}

// ---------------- MFMA GEMM: Y(chunk layout) = half( act(A) @ W ) ----------------
// Y layout: Y[chunk][n][32] halves, chunk = feature>>5.
template <int ACT>
__device__ __forceinline__ float act_f(float x) {
  if (ACT == 1) return x > 0.f ? x : expm1f(x);
  if (ACT == 2) return 0.5f * x * (1.0f + erff(x * 0.70710678118654752440f));
  return x;
}

template <int ACT, typename AT>
__global__ __launch_bounds__(256) void k_gemm(const AT* __restrict__ A,
                                              const __half* __restrict__ Wt,
                                              __half* __restrict__ Y, int n) {
  const int wave = threadIdx.x >> 6;
  const int lane = threadIdx.x & 63;
  const int np = lane & 15;
  const int quad = lane >> 4;
  const int node = blockIdx.x * 64 + wave * 16 + np;
  const int nc = min(node, n - 1);

  half8 b[4];
#pragma unroll
  for (int s = 0; s < 4; ++s) {
    if constexpr (sizeof(AT) == 4) {
      // fp32 x: streamed once, nt-load keeps L2 for Y
      const float* ap = (const float*)A + (size_t)nc * D + s * 32 + quad * 8;
      float4 v0 = ld_nt((const float4*)ap);
      float4 v1 = ld_nt((const float4*)(ap + 4));
      b[s][0] = (_Float16)act_f<ACT>(v0.x); b[s][1] = (_Float16)act_f<ACT>(v0.y);
      b[s][2] = (_Float16)act_f<ACT>(v0.z); b[s][3] = (_Float16)act_f<ACT>(v0.w);
      b[s][4] = (_Float16)act_f<ACT>(v1.x); b[s][5] = (_Float16)act_f<ACT>(v1.y);
      b[s][6] = (_Float16)act_f<ACT>(v1.z); b[s][7] = (_Float16)act_f<ACT>(v1.w);
    } else {
      // h: written by previous agg (L2-resident) -> normal cached load
      half8 raw = *(const half8*)((const __half*)A + ((size_t)s * n + nc) * 32 + quad * 8);
#pragma unroll
      for (int t = 0; t < 8; ++t)
        b[s][t] = (_Float16)act_f<ACT>((float)raw[t]);
    }
  }

  floatx4 acc[8];
#pragma unroll
  for (int mt = 0; mt < 8; ++mt) acc[mt] = (floatx4){0.f, 0.f, 0.f, 0.f};

#pragma unroll
  for (int mt = 0; mt < 8; ++mt) {
#pragma unroll
    for (int s = 0; s < 4; ++s) {
      half8 a = *(const half8*)(Wt + (size_t)(mt * 16 + np) * D + s * 32 + quad * 8);
      acc[mt] = __builtin_amdgcn_mfma_f32_16x16x32_f16(a, b[s], acc[mt], 0, 0, 0);
    }
  }

  if (node < n) {
    // normal stores: Y must stay L2-resident for agg's gathers
#pragma unroll
    for (int mt = 0; mt < 8; ++mt) {
      H4 hv;
      hv.a = __floats2half2_rn(acc[mt][0], acc[mt][1]);
      hv.b = __floats2half2_rn(acc[mt][2], acc[mt][3]);
      int f0 = mt * 16 + quad * 4;
      *(H4*)(Y + ((size_t)(f0 >> 5) * n + node) * 32 + (f0 & 31)) = hv;
    }
  }
}

// -------- aggregation (chunked, L2-resident gathers) --------
__device__ __forceinline__ void fmacc8(float* acc, float c, const H8& y) {
  float2 f;
  f = __half22float2(y.h[0]); acc[0] += c * f.x; acc[1] += c * f.y;
  f = __half22float2(y.h[1]); acc[2] += c * f.x; acc[3] += c * f.y;
  f = __half22float2(y.h[2]); acc[4] += c * f.x; acc[5] += c * f.y;
  f = __half22float2(y.h[3]); acc[6] += c * f.x; acc[7] += c * f.y;
}

__device__ __forceinline__ float cdecode(unsigned int u) {
  return __half2float(__ushort_as_half((unsigned short)(u & 0xffffu)));
}

template <int PRELU, typename OutT>
__global__ __launch_bounds__(256) void k_agg(const __half* __restrict__ Y,
                                             const int* __restrict__ offs,
                                             const unsigned int* __restrict__ ecf2,
                                             const float* __restrict__ dinv,
                                             const float* __restrict__ bias,
                                             const float* __restrict__ pw,
                                             OutT* __restrict__ OUT, int n) {
  const int chunk = blockIdx.x & 3;
  const int t = threadIdx.x;
  const int node = (blockIdx.x >> 2) * 32 + (t >> 3);
  const int sub = (t >> 2) & 1;   // edge half-group
  const int j = t & 3;            // 16B piece of the 64B chunk
  if (node >= n) return;
  const __half* Yc = Y + (size_t)chunk * n * 32;
  float dc = dinv[node];
  float acc[8] = {0.f, 0.f, 0.f, 0.f, 0.f, 0.f, 0.f, 0.f};
  if (sub == 0) {
    H8 ys = *(const H8*)(Yc + (size_t)node * 32 + j * 8);
    fmacc8(acc, dc, ys);
  }
  int e0 = offs[node], e1 = offs[node + 1];
  int e = e0 + sub;
  for (; e + 6 < e1; e += 8) {   // 4 gathers in flight per lane
    unsigned int u0 = ld_nt(&ecf2[e]),     u1 = ld_nt(&ecf2[e + 2]);
    unsigned int u2 = ld_nt(&ecf2[e + 4]), u3 = ld_nt(&ecf2[e + 6]);
    H8 y0 = *(const H8*)(Yc + (size_t)(u0 >> 16) * 32 + j * 8);
    H8 y1 = *(const H8*)(Yc + (size_t)(u1 >> 16) * 32 + j * 8);
    H8 y2 = *(const H8*)(Yc + (size_t)(u2 >> 16) * 32 + j * 8);
    H8 y3 = *(const H8*)(Yc + (size_t)(u3 >> 16) * 32 + j * 8);
    fmacc8(acc, cdecode(u0), y0);
    fmacc8(acc, cdecode(u1), y1);
    fmacc8(acc, cdecode(u2), y2);
    fmacc8(acc, cdecode(u3), y3);
  }
  for (; e + 2 < e1; e += 4) {   // 2 gathers in flight (common case)
    unsigned int u0 = ld_nt(&ecf2[e]), u1 = ld_nt(&ecf2[e + 2]);
    H8 y0 = *(const H8*)(Yc + (size_t)(u0 >> 16) * 32 + j * 8);
    H8 y1 = *(const H8*)(Yc + (size_t)(u1 >> 16) * 32 + j * 8);
    fmacc8(acc, cdecode(u0), y0);
    fmacc8(acc, cdecode(u1), y1);
  }
  for (; e < e1; e += 2) {
    unsigned int u = ld_nt(&ecf2[e]);
    H8 y = *(const H8*)(Yc + (size_t)(u >> 16) * 32 + j * 8);
    fmacc8(acc, cdecode(u), y);
  }
#pragma unroll
  for (int i = 0; i < 8; ++i) acc[i] += __shfl_xor(acc[i], 4, 64);
  float4 b4 = *(const float4*)(bias + chunk * 32 + j * 8 + sub * 4);
  float o[4];
  o[0] = dc * acc[sub * 4 + 0] + b4.x;
  o[1] = dc * acc[sub * 4 + 1] + b4.y;
  o[2] = dc * acc[sub * 4 + 2] + b4.z;
  o[3] = dc * acc[sub * 4 + 3] + b4.w;
  if (PRELU) {
    float wv = *pw;
#pragma unroll
    for (int i = 0; i < 4; ++i) o[i] = o[i] >= 0.f ? o[i] : wv * o[i];
  }
  if constexpr (sizeof(OutT) == 4) {
    // final fp32 output: never read again -> nt store
    st_nt16((float*)OUT + (size_t)node * D + chunk * 32 + j * 8 + sub * 4,
            make_float4(o[0], o[1], o[2], o[3]));
  } else {
    // h feeds next GEMM -> normal cached store
    H4 hv;
    hv.a = __floats2half2_rn(o[0], o[1]);
    hv.b = __floats2half2_rn(o[2], o[3]);
    *(H4*)((__half*)OUT + ((size_t)chunk * n + node) * 32 + j * 8 + sub * 4) = hv;
  }
}

// ---------------- launch ----------------
extern "C" void kernel_launch(void* const* d_in, const int* in_sizes, int n_in,
                              void* d_out, int out_size, void* d_ws, size_t ws_size,
                              hipStream_t stream) {
  const float* x  = (const float*)d_in[0];
  const int*   ei = (const int*)d_in[1];
  const float* w  = (const float*)d_in[2];
  const float* W1 = (const float*)d_in[3];
  const float* b1 = (const float*)d_in[4];
  const float* W2 = (const float*)d_in[5];
  const float* b2 = (const float*)d_in[6];
  const float* W3 = (const float*)d_in[7];
  const float* b3 = (const float*)d_in[8];
  const float* pw = (const float*)d_in[9];
  const int N = in_sizes[0] / D;
  const int E = in_sizes[2];
  float* out = (float*)d_out;

  char* wsb = (char*)d_ws;
  size_t off = 0;
  auto alloc = [&](size_t bytes) {
    void* p = wsb + off;
    off = (off + bytes + 255) & ~(size_t)255;
    return p;
  };
  float*        dinv = (float*)alloc((size_t)N * 4);
  int*          cnt  = (int*)alloc((size_t)N * 4);
  int*          offs = (int*)alloc((size_t)(N + 1) * 4);
  int*          bsum = (int*)alloc(256 * 4);
  int*          boff = (int*)alloc(256 * 4);
  int2*         ecf  = (int2*)alloc((size_t)E * 8);
  unsigned int* ecf2 = (unsigned int*)alloc((size_t)E * 4);
  __half*       Wt   = (__half*)alloc((size_t)3 * D * D * 2);
  __half*       Y    = (__half*)alloc((size_t)N * D * 2);
  __half*       h    = (__half*)alloc((size_t)N * D * 2);
  // transient buffers aliased into Y (dead before first GEMM writes Y): 8B/edge < N*D*2
  unsigned int* rcp  = (unsigned int*)Y;
  int*          pos  = (int*)((char*)Y + (size_t)E * 4);

  const int nb = (N + 255) / 256;
  const int eb = (E + 255) / 256;

  hipLaunchKernelGGL(k_init,    dim3(3 + nb), dim3(256), 0, stream, W1, W2, W3, Wt, cnt, N);
  hipLaunchKernelGGL(k_pos,     dim3(eb), dim3(256), 0, stream, ei, cnt, rcp, pos, E, N);
  hipLaunchKernelGGL(k_scan1,   dim3(nb), dim3(256), 0, stream, cnt, offs, bsum, N);
  hipLaunchKernelGGL(k_scan2,   dim3(1),  dim3(256), 0, stream, bsum, boff, nb);
  hipLaunchKernelGGL(k_scan3,   dim3(nb), dim3(256), 0, stream, offs, boff, N, E);
  hipLaunchKernelGGL(k_fill,    dim3(eb), dim3(256), 0, stream, rcp, pos, w, offs, ecf, E);
  hipLaunchKernelGGL(k_degdinv, dim3(nb), dim3(256), 0, stream, ecf, offs, dinv, N);
  hipLaunchKernelGGL(k_coef,    dim3(eb), dim3(256), 0, stream, ecf, dinv, ecf2, E);

  const int gb = (N + 63) / 64;
  const int ab = 4 * ((N + 31) / 32);

  hipLaunchKernelGGL((k_gemm<0, float>),  dim3(gb), dim3(256), 0, stream, x, Wt,             Y, N);
  hipLaunchKernelGGL((k_agg<0, __half>),  dim3(ab), dim3(256), 0, stream, Y, offs, ecf2, dinv, b1, pw, h, N);
  hipLaunchKernelGGL((k_gemm<1, __half>), dim3(gb), dim3(256), 0, stream, h, Wt + D * D,     Y, N);
  hipLaunchKernelGGL((k_agg<0, __half>),  dim3(ab), dim3(256), 0, stream, Y, offs, ecf2, dinv, b2, pw, h, N);
  hipLaunchKernelGGL((k_gemm<2, __half>), dim3(gb), dim3(256), 0, stream, h, Wt + 2 * D * D, Y, N);
  hipLaunchKernelGGL((k_agg<1, float>),   dim3(ab), dim3(256), 0, stream, Y, offs, ecf2, dinv, b3, pw, out, N);
}